// Round 4
// baseline (1196.904 us; speedup 1.0000x reference)
//
#include <hip/hip_runtime.h>
#include <stdint.h>

constexpr int SEQ    = 2048;
constexpr int DMODEL = 2048;
constexpr int NHEADS = 16;
constexpr int NKVH   = 4;
constexpr int HDIM   = 128;
constexpr int DFFN   = 8192;
constexpr int BATCH  = 2;
constexpr int MTOK   = BATCH * SEQ;   // 4096 tokens
constexpr int KKEEP  = DFFN / 2;      // 4096

typedef __bf16 bf16x8 __attribute__((ext_vector_type(8)));
typedef float  f32x4  __attribute__((ext_vector_type(4)));
typedef float  f32x16 __attribute__((ext_vector_type(16)));
typedef unsigned short u16;
typedef unsigned int   u32;

__device__ __forceinline__ u16 f2bu(float f) {  // f32 -> bf16 bits, RNE
  u32 x = __builtin_bit_cast(u32, f);
  return (u16)((x + 0x7FFFu + ((x >> 16) & 1u)) >> 16);
}
__device__ __forceinline__ float b2f(u16 u) {
  u32 v = ((u32)u) << 16;
  return __builtin_bit_cast(float, v);
}
__device__ __forceinline__ void gl_lds16(const void* g, void* l) {
  // 16B per lane; LDS dest = wave-uniform base + lane*16
  __builtin_amdgcn_global_load_lds((const __attribute__((address_space(1))) u32*)g,
                                   (__attribute__((address_space(3))) u32*)l, 16, 0, 0);
}

// ---------------- weight convert f32 -> bf16 ----------------
__global__ __launch_bounds__(256) void cvt_kernel(const float* __restrict__ in,
                                                  u16* __restrict__ out, int n) {
  int i = (blockIdx.x * 256 + threadIdx.x) * 4;
  if (i >= n) return;
  float4 v = *(const float4*)(in + i);
  uint2 pk;
  pk.x = (u32)f2bu(v.x) | ((u32)f2bu(v.y) << 16);
  pk.y = (u32)f2bu(v.z) | ((u32)f2bu(v.w) << 16);
  *(uint2*)(out + i) = pk;
}

// ---------------- RMSNorm: f32 row -> bf16 row ----------------
__global__ __launch_bounds__(256) void rmsnorm_kernel(const float* __restrict__ in,
                                                      const float* __restrict__ w,
                                                      u16* __restrict__ out) {
  const int tid = threadIdx.x;
  const size_t row = blockIdx.x;
  const float* x = in + row * DMODEL;
  float4 v0 = *(const float4*)(x + tid * 4);
  float4 v1 = *(const float4*)(x + 1024 + tid * 4);
  float s = v0.x*v0.x + v0.y*v0.y + v0.z*v0.z + v0.w*v0.w
          + v1.x*v1.x + v1.y*v1.y + v1.z*v1.z + v1.w*v1.w;
#pragma unroll
  for (int off = 1; off < 64; off <<= 1) s += __shfl_xor(s, off, 64);
  __shared__ float wsum[4];
  if ((tid & 63) == 0) wsum[tid >> 6] = s;
  __syncthreads();
  s = wsum[0] + wsum[1] + wsum[2] + wsum[3];
  const float rinv = rsqrtf(s * (1.0f / DMODEL) + 1e-6f);
  u16* o = out + row * DMODEL;
#pragma unroll
  for (int part = 0; part < 2; ++part) {
    int c = part * 1024 + tid * 4;
    float4 vv = (part == 0) ? v0 : v1;
    float4 wv = *(const float4*)(w + c);
    uint2 pk;
    pk.x = (u32)f2bu(vv.x * rinv * wv.x) | ((u32)f2bu(vv.y * rinv * wv.y) << 16);
    pk.y = (u32)f2bu(vv.z * rinv * wv.z) | ((u32)f2bu(vv.w * rinv * wv.w) << 16);
    *(uint2*)(o + c) = pk;
  }
}

// ---------------- GEMM C[M,N] = A[M,K] @ B[N,K]^T (bf16 row-major) --------
// Ring-4 pipelined: BK=32, 4 LDS buffers, counted vmcnt(8), raw barriers.
// Iter t: computes buf[t&3], stages tile t+3 into buf[(t+3)&3] (freed after
// iter t-1's barrier -> WAR-safe). vmcnt(8) at iter end (4 loads/wave/tile,
// <=2 tiles outstanding) guarantees tile t+1 resident before iter t+1 reads.
// LDS layout (per 128x32 operand tile), 16B-unit address:
//   U(row,c) = (row>>1)*8 + ((c ^ ((row>>1)&3))<<1) + (row&1)   [2-way free]
// EPI: 0 = bf16 store, 1 = transposed V store, 2 = f32 + residual (res may
//      alias C), 3 = f32 silu
template <int EPI>
__global__ __launch_bounds__(256, 2)
void gemm_bt(const u16* __restrict__ A, const u16* __restrict__ B,
             void* __restrict__ C, const float* res,
             int M, int N, int K) {
  __shared__ u16 As[4][128 * 32];
  __shared__ u16 Bs[4][128 * 32];
  const int tid = threadIdx.x;
  const int wave = tid >> 6, lane = tid & 63;
  // XCD-aware block swizzle (T1); all grids have nwg % 8 == 0
  const int nwg = gridDim.x * gridDim.y;
  const int lin = blockIdx.y * gridDim.x + blockIdx.x;
  const int swz = (lin & 7) * (nwg >> 3) + (lin >> 3);
  const int m0 = (swz / gridDim.x) * 128, n0 = (swz % gridDim.x) * 128;
  const int fk = lane >> 4, fc = lane & 15;     // MFMA fragment indices
  const int wm = (wave >> 1) * 64, wn = (wave & 1) * 64;
  const int nt = K >> 5;
  f32x4 acc[4][4] = {};

  // staging: per operand 8 instructions of 1KB; this wave does i = wave*2+ii.
  // Linear LDS dest unit U = i*64+lane maps to (row,c) via the layout bijection.
  const int sU0 = wave * 128 + lane;            // ii=0: U = wave*2*64 + lane
  auto stage = [&](int buf, int t) {
    const int kt = t * 32;
#pragma unroll
    for (int ii = 0; ii < 2; ++ii) {
      const int i = wave * 2 + ii;
      const int U = sU0 + ii * 64;
      const int rp = U >> 3, w = U & 7;
      const int c = (w >> 1) ^ (rp & 3);
      const int row = (rp << 1) | (w & 1);
      gl_lds16(A + (size_t)(m0 + row) * K + kt + c * 8, &As[buf][i * 512]);
      gl_lds16(B + (size_t)(n0 + row) * K + kt + c * 8, &Bs[buf][i * 512]);
    }
  };

  stage(0, 0); stage(1, 1); stage(2, 2);
  asm volatile("s_waitcnt vmcnt(8)" ::: "memory");
  __builtin_amdgcn_s_barrier();

  for (int t = 0; t < nt; ++t) {
    if (t + 3 < nt) stage((t + 3) & 3, t + 3);
    const u16* Ab = As[t & 3];
    const u16* Bb = Bs[t & 3];
    bf16x8 a[4], b[4];
#pragma unroll
    for (int m = 0; m < 4; ++m) {
      int row = wm + m * 16 + fc;
      int U = ((row >> 1) << 3) + ((fk ^ ((row >> 1) & 3)) << 1) + (row & 1);
      a[m] = *(const bf16x8*)(Ab + U * 8);
    }
#pragma unroll
    for (int j = 0; j < 4; ++j) {
      int row = wn + j * 16 + fc;
      int U = ((row >> 1) << 3) + ((fk ^ ((row >> 1) & 3)) << 1) + (row & 1);
      b[j] = *(const bf16x8*)(Bb + U * 8);
    }
#pragma unroll
    for (int m = 0; m < 4; ++m)
#pragma unroll
      for (int j = 0; j < 4; ++j)
        acc[m][j] = __builtin_amdgcn_mfma_f32_16x16x32_bf16(a[m], b[j], acc[m][j], 0, 0, 0);
    asm volatile("s_waitcnt vmcnt(8)" ::: "memory");
    __builtin_amdgcn_s_barrier();
  }

  const int rb = fk * 4;  // C/D: col = lane&15, row = (lane>>4)*4 + reg
#pragma unroll
  for (int i = 0; i < 4; ++i) {
#pragma unroll
    for (int j = 0; j < 4; ++j) {
      int row = m0 + wm + i * 16 + rb;
      int col = n0 + wn + j * 16 + fc;
      f32x4 v = acc[i][j];
      if constexpr (EPI == 0) {
        u16* o = (u16*)C;
#pragma unroll
        for (int r = 0; r < 4; ++r) o[(size_t)(row + r) * N + col] = f2bu(v[r]);
      } else if constexpr (EPI == 1) {
        // vt[b][kvh][d][s] ; row = token (4 consecutive s), col = kvh*128+d
        u16* o = (u16*)C;
        int bb = row >> 11, s = row & (SEQ - 1);
        int kvh = col >> 7, d = col & (HDIM - 1);
        size_t base = (((size_t)bb * NKVH + kvh) * HDIM + d) * SEQ + s;
        uint2 pk;
        pk.x = (u32)f2bu(v[0]) | ((u32)f2bu(v[1]) << 16);
        pk.y = (u32)f2bu(v[2]) | ((u32)f2bu(v[3]) << 16);
        *(uint2*)(o + base) = pk;
      } else if constexpr (EPI == 2) {
        float* o = (float*)C;
#pragma unroll
        for (int r = 0; r < 4; ++r) {
          size_t idx = (size_t)(row + r) * N + col;
          float rv = res[idx];
          o[idx] = v[r] + rv;
        }
      } else {  // EPI == 3 : silu
        float* o = (float*)C;
#pragma unroll
        for (int r = 0; r < 4; ++r) {
          float g = v[r];
          o[(size_t)(row + r) * N + col] = g / (1.0f + __expf(-g));
        }
      }
    }
  }
}

// ---------------- flash attention (causal GQA, swapped-QK, 32x32 MFMA) -----
// block = 4 waves; wave w owns q-strip [bx*128 + 32w, +32). KVBLK=32.
// S^T = mfma(K, Q): lane owns q-col (lane&31); 16 kv-scores per lane.
__global__ __launch_bounds__(256, 2)
void attn_kernel(const u16* __restrict__ Q, const u16* __restrict__ Kb,
                 const u16* __restrict__ Vt, u16* __restrict__ O) {
  __shared__ u16 Ksh[2 * 32 * 128];   // [buf][kv][d], chunk^(kv&15) swizzle
  __shared__ u16 Vsh[2 * 128 * 32];   // [buf][d][kv], chunk^((d>>1)&3) swizzle
  const int tid = threadIdx.x, wave = tid >> 6, lane = tid & 63;
  const int half = lane >> 5, l31 = lane & 31;
  // XCD swizzle: dispatch d -> logical block (d%8)*64 + d/8 so each XCD
  // owns exactly one (b,kvh) -> its 1MB K+V stays in that XCD's L2.
  const int d_lin = blockIdx.x + gridDim.x * (blockIdx.y + gridDim.y * blockIdx.z);
  const int lin = (d_lin & 7) * 64 + (d_lin >> 3);
  const int bx = lin & 15, h = (lin >> 4) & 15, b = lin >> 8;
  const int kvh = h >> 2;
  const int qw = bx * 128 + wave * 32;
  const float SC = 0.08838834764831845f;  // 1/sqrt(128)
  const int ntb = bx * 4 + 4;             // staged tiles per block
  const int nmy = bx * 4 + wave;          // last tile index this wave computes

  // persistent Q fragments: qf[s] lane: Q[qw + l31][s*16 + half*8 + j]
  bf16x8 qf[8];
  {
    const u16* qp = Q + ((size_t)(b * SEQ + qw + l31)) * DMODEL + h * HDIM + half * 8;
#pragma unroll
    for (int s = 0; s < 8; ++s) qf[s] = *(const bf16x8*)(qp + s * 16);
  }
  f32x16 oacc[4] = {};
  float m_run = -1e30f, l_run = 0.0f;
  const size_t vbase = ((size_t)(b * NKVH + kvh)) * HDIM * SEQ;
  const u16* kbase = Kb + (size_t)b * SEQ * (NKVH * HDIM) + kvh * HDIM;

  auto stage = [&](int bi, int k0) {
    u16* Kd = Ksh + bi * 4096;
    u16* Vd = Vsh + bi * 4096;
#pragma unroll
    for (int ii = 0; ii < 2; ++ii) {
      int inst = wave * 2 + ii;
      {  // K: instr covers kv rows 4*inst..+3, 256B each
        int row = inst * 4 + (lane >> 4);
        int c = (lane & 15) ^ (row & 15);
        gl_lds16(kbase + (size_t)(k0 + row) * (NKVH * HDIM) + c * 8, Kd + inst * 512);
      }
      {  // V^T: instr covers d rows 16*inst..+15, 64B each
        int row = inst * 16 + (lane >> 2);
        int c = (lane & 3) ^ ((row >> 1) & 3);
        gl_lds16(Vt + vbase + (size_t)row * SEQ + k0 + c * 8, Vd + inst * 512);
      }
    }
  };

  stage(0, 0);
  __syncthreads();

  for (int t = 0; t < ntb; ++t) {
    if (t + 1 < ntb) stage((t + 1) & 1, (t + 1) * 32);
    if (t <= nmy) {
      const u16* Kd = Ksh + (t & 1) * 4096;
      const u16* Vd = Vsh + (t & 1) * 4096;
      // ---- S^T[kv][q] over d=128 ----
      f32x16 st = {};
#pragma unroll
      for (int s = 0; s < 8; ++s) {
        int c = (half + 2 * s) ^ (l31 & 15);
        bf16x8 kf = *(const bf16x8*)(Kd + l31 * 128 + c * 8);
        st = __builtin_amdgcn_mfma_f32_32x32x16_bf16(kf, qf[s], st, 0, 0, 0);
      }
      // ---- softmax (lane owns q = qw + l31; kv(r) = (r&3)+8*(r>>2)+4*half)
      const bool diag = (t * 32 == qw);
      float sv[16];
#pragma unroll
      for (int r = 0; r < 16; ++r) {
        float x = st[r] * SC;
        if (diag) {
          int kvl = (r & 3) + 8 * (r >> 2) + 4 * half;
          if (kvl > l31) x = -1e30f;
        }
        sv[r] = x;
      }
      float mx = sv[0];
#pragma unroll
      for (int r = 1; r < 16; ++r) mx = fmaxf(mx, sv[r]);
      mx = fmaxf(mx, __shfl_xor(mx, 32, 64));
      if (__any(mx > m_run + 4.0f)) {   // defer-max (exact): rescale rarely
        float mnew = fmaxf(m_run, mx);
        float alpha = __expf(m_run - mnew);
        m_run = mnew;
        l_run *= alpha;
#pragma unroll
        for (int r = 0; r < 16; ++r) {
          float ar = __shfl(alpha, (r & 3) + 8 * (r >> 2) + 4 * half, 64);
#pragma unroll
          for (int dt = 0; dt < 4; ++dt) oacc[dt][r] *= ar;
        }
      }
      float p[16];
      float rs = 0.0f;
#pragma unroll
      for (int r = 0; r < 16; ++r) { p[r] = __expf(sv[r] - m_run); rs += p[r]; }
      rs += __shfl_xor(rs, 32, 64);
      l_run += rs;
      // ---- P -> bf16 A-fragments via half-swap ----
      u32 c01 = (u32)f2bu(p[0])  | ((u32)f2bu(p[1])  << 16);
      u32 c23 = (u32)f2bu(p[2])  | ((u32)f2bu(p[3])  << 16);
      u32 c45 = (u32)f2bu(p[4])  | ((u32)f2bu(p[5])  << 16);
      u32 c67 = (u32)f2bu(p[6])  | ((u32)f2bu(p[7])  << 16);
      u32 c89 = (u32)f2bu(p[8])  | ((u32)f2bu(p[9])  << 16);
      u32 cAB = (u32)f2bu(p[10]) | ((u32)f2bu(p[11]) << 16);
      u32 cCD = (u32)f2bu(p[12]) | ((u32)f2bu(p[13]) << 16);
      u32 cEF = (u32)f2bu(p[14]) | ((u32)f2bu(p[15]) << 16);
      u32 paw[2][4];
      {
        u32 sA = __shfl_xor(c01, 32, 64), sB = __shfl_xor(c23, 32, 64);
        u32 sC = __shfl_xor(c45, 32, 64), sD = __shfl_xor(c67, 32, 64);
        paw[0][0] = half ? sC : c01;  paw[0][1] = half ? sD : c23;
        paw[0][2] = half ? c45 : sA;  paw[0][3] = half ? c67 : sB;
      }
      {
        u32 sA = __shfl_xor(c89, 32, 64), sB = __shfl_xor(cAB, 32, 64);
        u32 sC = __shfl_xor(cCD, 32, 64), sD = __shfl_xor(cEF, 32, 64);
        paw[1][0] = half ? sC : c89;  paw[1][1] = half ? sD : cAB;
        paw[1][2] = half ? cCD : sA;  paw[1][3] = half ? cEF : sB;
      }
      // ---- PV: oacc[dt][q-rows] += P[q][kv] * V[kv][d] ----
#pragma unroll
      for (int ks = 0; ks < 2; ++ks) {
        bf16x8 paf = __builtin_bit_cast(bf16x8, *(uint4*)&paw[ks][0]);
#pragma unroll
        for (int dt = 0; dt < 4; ++dt) {
          int row = dt * 32 + l31;
          int c = (half + 2 * ks) ^ ((row >> 1) & 3);
          bf16x8 vf = *(const bf16x8*)(Vd + row * 32 + c * 8);
          oacc[dt] = __builtin_amdgcn_mfma_f32_32x32x16_bf16(paf, vf, oacc[dt], 0, 0, 0);
        }
      }
    }
    __syncthreads();
  }

  // ---- epilogue: O[q][d] / l[q] ----
  float rinv = 1.0f / l_run;
  u16* ob = O + ((size_t)(b * SEQ + qw)) * DMODEL + h * HDIM + l31;
#pragma unroll
  for (int r = 0; r < 16; ++r) {
    int qr = (r & 3) + 8 * (r >> 2) + 4 * half;
    float ir = __shfl(rinv, qr, 64);
#pragma unroll
    for (int dt = 0; dt < 4; ++dt)
      ob[(size_t)qr * DMODEL + dt * 32] = f2bu(oacc[dt][r] * ir);
  }
}

// ---------------- top-k (exact radix select) + gate*up, in-place over up ---
__global__ __launch_bounds__(256)
void topk_kernel(const float* __restrict__ gate, u16* __restrict__ upact) {
  __shared__ u32 sabs[DFFN];       // silu(gate) f32 bits
  __shared__ u32 hist[4][256];
  __shared__ u32 ss[257];
  __shared__ u32 sh_prefix, sh_rem;
  const int tid = threadIdx.x, wave = tid >> 6;
  const size_t row = blockIdx.x;
  const float* g = gate + row * DFFN;
  for (int it = 0; it < 4; ++it) {
    int e = it * 2048 + tid * 8;
    float4 a = *(const float4*)(g + e);
    float4 b = *(const float4*)(g + e + 4);
    sabs[e + 0] = __builtin_bit_cast(u32, a.x);
    sabs[e + 1] = __builtin_bit_cast(u32, a.y);
    sabs[e + 2] = __builtin_bit_cast(u32, a.z);
    sabs[e + 3] = __builtin_bit_cast(u32, a.w);
    sabs[e + 4] = __builtin_bit_cast(u32, b.x);
    sabs[e + 5] = __builtin_bit_cast(u32, b.y);
    sabs[e + 6] = __builtin_bit_cast(u32, b.z);
    sabs[e + 7] = __builtin_bit_cast(u32, b.w);
  }
  if (tid == 0) { sh_prefix = 0; sh_rem = KKEEP; }
  __syncthreads();
  for (int pass = 0; pass < 4; ++pass) {
    const int p = 24 - pass * 8;
    const u32 mask_hi = (pass == 0) ? 0u : (0xFFFFFFFFu << (p + 8));
    for (int i = tid; i < 1024; i += 256) ((u32*)hist)[i] = 0;
    __syncthreads();
    const u32 prefix = sh_prefix, rem = sh_rem;
    for (int it = 0; it < 4; ++it) {
      int e = it * 2048 + tid * 8;
#pragma unroll
      for (int j = 0; j < 8; ++j) {
        u32 mg = sabs[e + j] & 0x7FFFFFFFu;
        if ((mg & mask_hi) == (prefix & mask_hi))
          atomicAdd(&hist[wave][(mg >> p) & 0xFF], 1u);
      }
    }
    __syncthreads();
    ss[tid] = hist[0][tid] + hist[1][tid] + hist[2][tid] + hist[3][tid];
    if (tid == 0) ss[256] = 0;
    __syncthreads();
    for (int off = 1; off < 256; off <<= 1) {
      u32 v = (tid + off < 256) ? ss[tid + off] : 0u;
      __syncthreads();
      ss[tid] += v;
      __syncthreads();
    }
    if (ss[tid] >= rem && ss[tid + 1] < rem) {
      sh_prefix = prefix | ((u32)tid << p);
      sh_rem = rem - ss[tid + 1];
    }
    __syncthreads();
  }
  const u32 thr = sh_prefix;
  u16* ua = upact + row * DFFN;
  for (int it = 0; it < 4; ++it) {
    int e = it * 2048 + tid * 8;
    uint4 uv = *(const uint4*)(ua + e);
    const u16* up16 = (const u16*)&uv;
    u16 outp[8];
#pragma unroll
    for (int j = 0; j < 8; ++j) {
      u32 bits = sabs[e + j];
      u32 mg = bits & 0x7FFFFFFFu;
      float gg = __builtin_bit_cast(float, bits);
      float prod = (mg >= thr) ? gg * b2f(up16[j]) : 0.0f;
      outp[j] = f2bu(prod);
    }
    uint4 ov;
    ov.x = (u32)outp[0] | ((u32)outp[1] << 16);
    ov.y = (u32)outp[2] | ((u32)outp[3] << 16);
    ov.z = (u32)outp[4] | ((u32)outp[5] << 16);
    ov.w = (u32)outp[6] | ((u32)outp[7] << 16);
    *(uint4*)(ua + e) = ov;
  }
}

// ---------------- launcher ----------------
extern "C" void kernel_launch(void* const* d_in, const int* in_sizes, int n_in,
                              void* d_out, int out_size, void* d_ws, size_t ws_size,
                              hipStream_t stream) {
  const float* hidden = (const float*)d_in[0];
  const float* wq = (const float*)d_in[1];
  const float* wk = (const float*)d_in[2];
  const float* wv = (const float*)d_in[3];
  const float* wo = (const float*)d_in[4];
  const float* ln1 = (const float*)d_in[5];
  const float* ln2 = (const float*)d_in[6];
  const float* wg = (const float*)d_in[7];
  const float* wu = (const float*)d_in[8];
  const float* wd = (const float*)d_in[9];
  float* out = (float*)d_out;
  (void)in_sizes; (void)n_in; (void)out_size;

  // ---- workspace layout (lifetime-aliased, ~196 MB total) ----
  size_t off = 0;
  auto alloc = [&](size_t n) { char* r = (char*)d_ws + off; off += (n + 255) & ~(size_t)255; return r; };
  u16* wq_b = (u16*)alloc((size_t)DMODEL * DMODEL * 2);      // 8 MB
  u16* wk_b = (u16*)alloc((size_t)NKVH * HDIM * DMODEL * 2); // 2 MB
  u16* wv_b = (u16*)alloc((size_t)NKVH * HDIM * DMODEL * 2); // 2 MB
  u16* wo_b = (u16*)alloc((size_t)DMODEL * DMODEL * 2);      // 8 MB
  u16* wg_b = (u16*)alloc((size_t)DFFN * DMODEL * 2);        // 32 MB
  u16* tok  = (u16*)alloc((size_t)MTOK * DMODEL * 2);        // 16 MB: x -> o -> y
  u16* upb  = (u16*)alloc((size_t)MTOK * DFFN * 2);          // 64 MB
  char* S   = alloc((size_t)(MTOK / 2) * DFFN * 4);          // 64 MB shared region
  // phase 1 of S: qb(16) kb(4) vtb(4) wu_b(32)
  u16* qb   = (u16*)S;
  u16* kb   = (u16*)(S + (size_t)MTOK * DMODEL * 2);
  u16* vtb  = (u16*)(S + (size_t)MTOK * DMODEL * 2 + (size_t)MTOK * NKVH * HDIM * 2);
  u16* wu_b = (u16*)(S + (size_t)MTOK * DMODEL * 2 + 2 * (size_t)MTOK * NKVH * HDIM * 2);
  // phase 2 of S: gate half (f32, 2048 x 8192)
  float* gateh = (float*)S;
  // phase 3 of S: wd_b (32 MB)
  u16* wd_b = (u16*)S;
  const size_t needed = off;
  if (ws_size < needed) return;  // clean fast-fail (diagnostic) instead of OOB hang

  auto cvt = [&](const float* src, u16* dst, size_t n) {
    cvt_kernel<<<dim3((unsigned)(n / 1024)), 256, 0, stream>>>(src, dst, (int)n);
  };
  cvt(wq, wq_b, (size_t)DMODEL * DMODEL);
  cvt(wk, wk_b, (size_t)NKVH * HDIM * DMODEL);
  cvt(wv, wv_b, (size_t)NKVH * HDIM * DMODEL);
  cvt(wo, wo_b, (size_t)DMODEL * DMODEL);
  cvt(wg, wg_b, (size_t)DFFN * DMODEL);
  cvt(wu, wu_b, (size_t)DFFN * DMODEL);

  // x = rmsnorm(hidden, ln1)
  rmsnorm_kernel<<<MTOK, 256, 0, stream>>>(hidden, ln1, tok);

  gemm_bt<0><<<dim3(DMODEL / 128, MTOK / 128), 256, 0, stream>>>(
      tok, wq_b, qb, nullptr, MTOK, DMODEL, DMODEL);
  gemm_bt<0><<<dim3(NKVH * HDIM / 128, MTOK / 128), 256, 0, stream>>>(
      tok, wk_b, kb, nullptr, MTOK, NKVH * HDIM, DMODEL);
  gemm_bt<1><<<dim3(NKVH * HDIM / 128, MTOK / 128), 256, 0, stream>>>(
      tok, wv_b, vtb, nullptr, MTOK, NKVH * HDIM, DMODEL);

  // o -> tok (x dead)
  attn_kernel<<<dim3(SEQ / 128, NHEADS, BATCH), 256, 0, stream>>>(qb, kb, vtb, tok);

  // h = hidden + o @ wo^T   -> stored in d_out
  gemm_bt<2><<<dim3(DMODEL / 128, MTOK / 128), 256, 0, stream>>>(
      tok, wo_b, out, hidden, MTOK, DMODEL, DMODEL);

  // y = rmsnorm(h, ln2) -> tok (o dead)
  rmsnorm_kernel<<<MTOK, 256, 0, stream>>>(out, ln2, tok);

  // up = y @ wu^T (bf16) — must complete before S is reused for gate halves
  gemm_bt<0><<<dim3(DFFN / 128, MTOK / 128), 256, 0, stream>>>(
      tok, wu_b, upb, nullptr, MTOK, DFFN, DMODEL);

  // gate halves: silu(y @ wg^T) f32 -> topk+multiply in-place into upb
  for (int half = 0; half < 2; ++half) {
    const u16* yh = tok + (size_t)half * (MTOK / 2) * DMODEL;
    u16* uph = upb + (size_t)half * (MTOK / 2) * DFFN;
    gemm_bt<3><<<dim3(DFFN / 128, (MTOK / 2) / 128), 256, 0, stream>>>(
        yh, wg_b, gateh, nullptr, MTOK / 2, DFFN, DMODEL);
    topk_kernel<<<MTOK / 2, 256, 0, stream>>>(gateh, uph);
  }

  // wd -> bf16 (into S, gate halves dead)
  cvt(wd, wd_b, (size_t)DMODEL * DFFN);

  // out = h + act @ wd^T  (in-place residual over d_out)
  gemm_bt<2><<<dim3(DMODEL / 128, MTOK / 128), 256, 0, stream>>>(
      upb, wd_b, out, out, MTOK, DMODEL, DFFN);
}

// Round 5
// 1052.179 us; speedup vs baseline: 1.1375x; 1.1375x over previous
//
#include <hip/hip_runtime.h>
#include <stdint.h>

constexpr int SEQ    = 2048;
constexpr int DMODEL = 2048;
constexpr int NHEADS = 16;
constexpr int NKVH   = 4;
constexpr int HDIM   = 128;
constexpr int DFFN   = 8192;
constexpr int BATCH  = 2;
constexpr int MTOK   = BATCH * SEQ;   // 4096 tokens
constexpr int KKEEP  = DFFN / 2;      // 4096

typedef __bf16 bf16x8 __attribute__((ext_vector_type(8)));
typedef float  f32x4  __attribute__((ext_vector_type(4)));
typedef float  f32x16 __attribute__((ext_vector_type(16)));
typedef unsigned short u16;
typedef unsigned int   u32;

__device__ __forceinline__ u16 f2bu(float f) {  // f32 -> bf16 bits, RNE
  u32 x = __builtin_bit_cast(u32, f);
  return (u16)((x + 0x7FFFu + ((x >> 16) & 1u)) >> 16);
}
__device__ __forceinline__ float b2f(u16 u) {
  u32 v = ((u32)u) << 16;
  return __builtin_bit_cast(float, v);
}
__device__ __forceinline__ void gl_lds16(const void* g, void* l) {
  // 16B per lane; LDS dest = wave-uniform base + lane*16
  __builtin_amdgcn_global_load_lds((const __attribute__((address_space(1))) u32*)g,
                                   (__attribute__((address_space(3))) u32*)l, 16, 0, 0);
}

// ---------------- weight convert f32 -> bf16 ----------------
__global__ __launch_bounds__(256) void cvt_kernel(const float* __restrict__ in,
                                                  u16* __restrict__ out, int n) {
  int i = (blockIdx.x * 256 + threadIdx.x) * 4;
  if (i >= n) return;
  float4 v = *(const float4*)(in + i);
  uint2 pk;
  pk.x = (u32)f2bu(v.x) | ((u32)f2bu(v.y) << 16);
  pk.y = (u32)f2bu(v.z) | ((u32)f2bu(v.w) << 16);
  *(uint2*)(out + i) = pk;
}

// ---------------- RMSNorm: f32 row -> bf16 row ----------------
__global__ __launch_bounds__(256) void rmsnorm_kernel(const float* __restrict__ in,
                                                      const float* __restrict__ w,
                                                      u16* __restrict__ out) {
  const int tid = threadIdx.x;
  const size_t row = blockIdx.x;
  const float* x = in + row * DMODEL;
  float4 v0 = *(const float4*)(x + tid * 4);
  float4 v1 = *(const float4*)(x + 1024 + tid * 4);
  float s = v0.x*v0.x + v0.y*v0.y + v0.z*v0.z + v0.w*v0.w
          + v1.x*v1.x + v1.y*v1.y + v1.z*v1.z + v1.w*v1.w;
#pragma unroll
  for (int off = 1; off < 64; off <<= 1) s += __shfl_xor(s, off, 64);
  __shared__ float wsum[4];
  if ((tid & 63) == 0) wsum[tid >> 6] = s;
  __syncthreads();
  s = wsum[0] + wsum[1] + wsum[2] + wsum[3];
  const float rinv = rsqrtf(s * (1.0f / DMODEL) + 1e-6f);
  u16* o = out + row * DMODEL;
#pragma unroll
  for (int part = 0; part < 2; ++part) {
    int c = part * 1024 + tid * 4;
    float4 vv = (part == 0) ? v0 : v1;
    float4 wv = *(const float4*)(w + c);
    uint2 pk;
    pk.x = (u32)f2bu(vv.x * rinv * wv.x) | ((u32)f2bu(vv.y * rinv * wv.y) << 16);
    pk.y = (u32)f2bu(vv.z * rinv * wv.z) | ((u32)f2bu(vv.w * rinv * wv.w) << 16);
    *(uint2*)(o + c) = pk;
  }
}

// ---------------- GEMM C[M,N] = A[M,K] @ B[N,K]^T (bf16 row-major) --------
// Min-2-phase pipeline (T3 minimum recipe): BK=64, double-buffered LDS,
// ONE raw barrier per K-step. Iter t: issue STAGE(t+1) into buf[(t+1)&1],
// then ds_read+32xMFMA from buf[t&1] (covers ~300cy of load flight), then
// vmcnt(0) (staged tile landed) + s_barrier (all waves done reading buf[t&1]
// -> next iter may overwrite it). Cross-wave visibility: each wave drains its
// own loads pre-barrier; barrier publishes.
// LDS chunk-XOR layout: row-major [row][8 chunks of 16B], slot c holds global
// chunk c^(row&7)  (measured 0 bank conflicts).
// EPI: 0 = bf16 store, 1 = transposed V store, 2 = f32 + residual (res may
//      alias C), 3 = f32 silu
template <int EPI>
__global__ __launch_bounds__(256, 2)
void gemm_bt(const u16* __restrict__ A, const u16* __restrict__ B,
             void* __restrict__ C, const float* res,
             int M, int N, int K) {
  __shared__ u16 As[2][128 * 64];
  __shared__ u16 Bs[2][128 * 64];
  const int tid = threadIdx.x;
  const int wave = tid >> 6, lane = tid & 63;
  // XCD-aware block swizzle (T1); all grids have nwg % 8 == 0
  const int nwg = gridDim.x * gridDim.y;
  const int lin = blockIdx.y * gridDim.x + blockIdx.x;
  const int swz = (lin & 7) * (nwg >> 3) + (lin >> 3);
  const int m0 = (swz / gridDim.x) * 128, n0 = (swz % gridDim.x) * 128;
  const int r_in = lane >> 3, chk = lane & 7;   // staging: 8 rows x 8 chunks / KB
  const int fk = lane >> 4, fc = lane & 15;     // MFMA fragment indices
  const int wm = (wave >> 1) * 64, wn = (wave & 1) * 64;
  const int nt = K >> 6;
  f32x4 acc[4][4] = {};

  auto stage = [&](int buf, int t) {
    const int kt = t * 64;
#pragma unroll
    for (int i = 0; i < 4; ++i) {
      int row = wave * 32 + i * 8 + r_in;
      int gc = chk ^ (row & 7);   // pre-swizzled source, linear LDS dest
      gl_lds16(A + (size_t)(m0 + row) * K + kt + gc * 8, &As[buf][(wave * 32 + i * 8) * 64]);
    }
#pragma unroll
    for (int i = 0; i < 4; ++i) {
      int row = wave * 32 + i * 8 + r_in;
      int gc = chk ^ (row & 7);
      gl_lds16(B + (size_t)(n0 + row) * K + kt + gc * 8, &Bs[buf][(wave * 32 + i * 8) * 64]);
    }
  };

  stage(0, 0);
  asm volatile("s_waitcnt vmcnt(0)" ::: "memory");
  __builtin_amdgcn_s_barrier();

  for (int t = 0; t < nt; ++t) {
    if (t + 1 < nt) stage((t + 1) & 1, t + 1);   // issue-early: overlaps MFMA below
    const u16* Ab = As[t & 1];
    const u16* Bb = Bs[t & 1];
#pragma unroll
    for (int kk = 0; kk < 2; ++kk) {
      bf16x8 a[4], b[4];
#pragma unroll
      for (int i = 0; i < 4; ++i) {
        int row = wm + i * 16 + fc;
        int c = (kk * 4 + fk) ^ (row & 7);
        a[i] = *(const bf16x8*)(Ab + row * 64 + c * 8);
      }
#pragma unroll
      for (int j = 0; j < 4; ++j) {
        int row = wn + j * 16 + fc;
        int c = (kk * 4 + fk) ^ (row & 7);
        b[j] = *(const bf16x8*)(Bb + row * 64 + c * 8);
      }
#pragma unroll
      for (int i = 0; i < 4; ++i)
#pragma unroll
        for (int j = 0; j < 4; ++j)
          acc[i][j] = __builtin_amdgcn_mfma_f32_16x16x32_bf16(a[i], b[j], acc[i][j], 0, 0, 0);
    }
    asm volatile("s_waitcnt vmcnt(0)" ::: "memory");  // staged loads landed (late drain)
    __builtin_amdgcn_s_barrier();
  }

  const int rb = fk * 4;  // C/D: col = lane&15, row = (lane>>4)*4 + reg
#pragma unroll
  for (int i = 0; i < 4; ++i) {
#pragma unroll
    for (int j = 0; j < 4; ++j) {
      int row = m0 + wm + i * 16 + rb;
      int col = n0 + wn + j * 16 + fc;
      f32x4 v = acc[i][j];
      if constexpr (EPI == 0) {
        u16* o = (u16*)C;
#pragma unroll
        for (int r = 0; r < 4; ++r) o[(size_t)(row + r) * N + col] = f2bu(v[r]);
      } else if constexpr (EPI == 1) {
        // vt[b][kvh][d][s] ; row = token (4 consecutive s), col = kvh*128+d
        u16* o = (u16*)C;
        int bb = row >> 11, s = row & (SEQ - 1);
        int kvh = col >> 7, d = col & (HDIM - 1);
        size_t base = (((size_t)bb * NKVH + kvh) * HDIM + d) * SEQ + s;
        uint2 pk;
        pk.x = (u32)f2bu(v[0]) | ((u32)f2bu(v[1]) << 16);
        pk.y = (u32)f2bu(v[2]) | ((u32)f2bu(v[3]) << 16);
        *(uint2*)(o + base) = pk;
      } else if constexpr (EPI == 2) {
        float* o = (float*)C;
#pragma unroll
        for (int r = 0; r < 4; ++r) {
          size_t idx = (size_t)(row + r) * N + col;
          float rv = res[idx];
          o[idx] = v[r] + rv;
        }
      } else {  // EPI == 3 : silu
        float* o = (float*)C;
#pragma unroll
        for (int r = 0; r < 4; ++r) {
          float g = v[r];
          o[(size_t)(row + r) * N + col] = g / (1.0f + __expf(-g));
        }
      }
    }
  }
}

// ---------------- flash attention (causal GQA, swapped-QK, 32x32 MFMA) -----
// block = 4 waves; wave w owns q-strip [bx*128 + 32w, +32). KVBLK=32.
// S^T = mfma(K, Q): lane owns q-col (lane&31); 16 kv-scores per lane.
__global__ __launch_bounds__(256, 2)
void attn_kernel(const u16* __restrict__ Q, const u16* __restrict__ Kb,
                 const u16* __restrict__ Vt, u16* __restrict__ O) {
  __shared__ u16 Ksh[2 * 32 * 128];   // [buf][kv][d], chunk^(kv&15) swizzle
  __shared__ u16 Vsh[2 * 128 * 32];   // [buf][d][kv], chunk^((d>>1)&3) swizzle
  const int tid = threadIdx.x, wave = tid >> 6, lane = tid & 63;
  const int half = lane >> 5, l31 = lane & 31;
  // XCD swizzle: dispatch d -> logical block (d%8)*64 + d/8 so each XCD
  // owns exactly one (b,kvh) -> its 1MB K+V stays in that XCD's L2.
  const int d_lin = blockIdx.x + gridDim.x * (blockIdx.y + gridDim.y * blockIdx.z);
  const int lin = (d_lin & 7) * 64 + (d_lin >> 3);
  const int bx = lin & 15, h = (lin >> 4) & 15, b = lin >> 8;
  const int kvh = h >> 2;
  const int qw = bx * 128 + wave * 32;
  const float SC = 0.08838834764831845f;  // 1/sqrt(128)
  const int ntb = bx * 4 + 4;             // staged tiles per block
  const int nmy = bx * 4 + wave;          // last tile index this wave computes

  // persistent Q fragments: qf[s] lane: Q[qw + l31][s*16 + half*8 + j]
  bf16x8 qf[8];
  {
    const u16* qp = Q + ((size_t)(b * SEQ + qw + l31)) * DMODEL + h * HDIM + half * 8;
#pragma unroll
    for (int s = 0; s < 8; ++s) qf[s] = *(const bf16x8*)(qp + s * 16);
  }
  f32x16 oacc[4] = {};
  float m_run = -1e30f, l_run = 0.0f;
  const size_t vbase = ((size_t)(b * NKVH + kvh)) * HDIM * SEQ;
  const u16* kbase = Kb + (size_t)b * SEQ * (NKVH * HDIM) + kvh * HDIM;

  auto stage = [&](int bi, int k0) {
    u16* Kd = Ksh + bi * 4096;
    u16* Vd = Vsh + bi * 4096;
#pragma unroll
    for (int ii = 0; ii < 2; ++ii) {
      int inst = wave * 2 + ii;
      {  // K: instr covers kv rows 4*inst..+3, 256B each
        int row = inst * 4 + (lane >> 4);
        int c = (lane & 15) ^ (row & 15);
        gl_lds16(kbase + (size_t)(k0 + row) * (NKVH * HDIM) + c * 8, Kd + inst * 512);
      }
      {  // V^T: instr covers d rows 16*inst..+15, 64B each
        int row = inst * 16 + (lane >> 2);
        int c = (lane & 3) ^ ((row >> 1) & 3);
        gl_lds16(Vt + vbase + (size_t)row * SEQ + k0 + c * 8, Vd + inst * 512);
      }
    }
  };

  stage(0, 0);
  __syncthreads();

  for (int t = 0; t < ntb; ++t) {
    if (t + 1 < ntb) stage((t + 1) & 1, (t + 1) * 32);
    if (t <= nmy) {
      const u16* Kd = Ksh + (t & 1) * 4096;
      const u16* Vd = Vsh + (t & 1) * 4096;
      // ---- S^T[kv][q] over d=128 ----
      f32x16 st = {};
#pragma unroll
      for (int s = 0; s < 8; ++s) {
        int c = (half + 2 * s) ^ (l31 & 15);
        bf16x8 kf = *(const bf16x8*)(Kd + l31 * 128 + c * 8);
        st = __builtin_amdgcn_mfma_f32_32x32x16_bf16(kf, qf[s], st, 0, 0, 0);
      }
      // ---- softmax (lane owns q = qw + l31; kv(r) = (r&3)+8*(r>>2)+4*half)
      const bool diag = (t * 32 == qw);
      float sv[16];
#pragma unroll
      for (int r = 0; r < 16; ++r) {
        float x = st[r] * SC;
        if (diag) {
          int kvl = (r & 3) + 8 * (r >> 2) + 4 * half;
          if (kvl > l31) x = -1e30f;
        }
        sv[r] = x;
      }
      float mx = sv[0];
#pragma unroll
      for (int r = 1; r < 16; ++r) mx = fmaxf(mx, sv[r]);
      mx = fmaxf(mx, __shfl_xor(mx, 32, 64));
      if (__any(mx > m_run + 4.0f)) {   // defer-max (exact): rescale rarely
        float mnew = fmaxf(m_run, mx);
        float alpha = __expf(m_run - mnew);
        m_run = mnew;
        l_run *= alpha;
#pragma unroll
        for (int r = 0; r < 16; ++r) {
          float ar = __shfl(alpha, (r & 3) + 8 * (r >> 2) + 4 * half, 64);
#pragma unroll
          for (int dt = 0; dt < 4; ++dt) oacc[dt][r] *= ar;
        }
      }
      float p[16];
      float rs = 0.0f;
#pragma unroll
      for (int r = 0; r < 16; ++r) { p[r] = __expf(sv[r] - m_run); rs += p[r]; }
      rs += __shfl_xor(rs, 32, 64);
      l_run += rs;
      // ---- P -> bf16 A-fragments via half-swap ----
      u32 c01 = (u32)f2bu(p[0])  | ((u32)f2bu(p[1])  << 16);
      u32 c23 = (u32)f2bu(p[2])  | ((u32)f2bu(p[3])  << 16);
      u32 c45 = (u32)f2bu(p[4])  | ((u32)f2bu(p[5])  << 16);
      u32 c67 = (u32)f2bu(p[6])  | ((u32)f2bu(p[7])  << 16);
      u32 c89 = (u32)f2bu(p[8])  | ((u32)f2bu(p[9])  << 16);
      u32 cAB = (u32)f2bu(p[10]) | ((u32)f2bu(p[11]) << 16);
      u32 cCD = (u32)f2bu(p[12]) | ((u32)f2bu(p[13]) << 16);
      u32 cEF = (u32)f2bu(p[14]) | ((u32)f2bu(p[15]) << 16);
      u32 paw[2][4];
      {
        u32 sA = __shfl_xor(c01, 32, 64), sB = __shfl_xor(c23, 32, 64);
        u32 sC = __shfl_xor(c45, 32, 64), sD = __shfl_xor(c67, 32, 64);
        paw[0][0] = half ? sC : c01;  paw[0][1] = half ? sD : c23;
        paw[0][2] = half ? c45 : sA;  paw[0][3] = half ? c67 : sB;
      }
      {
        u32 sA = __shfl_xor(c89, 32, 64), sB = __shfl_xor(cAB, 32, 64);
        u32 sC = __shfl_xor(cCD, 32, 64), sD = __shfl_xor(cEF, 32, 64);
        paw[1][0] = half ? sC : c89;  paw[1][1] = half ? sD : cAB;
        paw[1][2] = half ? cCD : sA;  paw[1][3] = half ? cEF : sB;
      }
      // ---- PV: oacc[dt][q-rows] += P[q][kv] * V[kv][d] ----
#pragma unroll
      for (int ks = 0; ks < 2; ++ks) {
        bf16x8 paf = __builtin_bit_cast(bf16x8, *(uint4*)&paw[ks][0]);
#pragma unroll
        for (int dt = 0; dt < 4; ++dt) {
          int row = dt * 32 + l31;
          int c = (half + 2 * ks) ^ ((row >> 1) & 3);
          bf16x8 vf = *(const bf16x8*)(Vd + row * 32 + c * 8);
          oacc[dt] = __builtin_amdgcn_mfma_f32_32x32x16_bf16(paf, vf, oacc[dt], 0, 0, 0);
        }
      }
    }
    __syncthreads();
  }

  // ---- epilogue: O[q][d] / l[q] ----
  float rinv = 1.0f / l_run;
  u16* ob = O + ((size_t)(b * SEQ + qw)) * DMODEL + h * HDIM + l31;
#pragma unroll
  for (int r = 0; r < 16; ++r) {
    int qr = (r & 3) + 8 * (r >> 2) + 4 * half;
    float ir = __shfl(rinv, qr, 64);
#pragma unroll
    for (int dt = 0; dt < 4; ++dt)
      ob[(size_t)qr * DMODEL + dt * 32] = f2bu(oacc[dt][r] * ir);
  }
}

// ---------------- top-k (exact radix select) + gate*up, in-place over up ---
__global__ __launch_bounds__(256)
void topk_kernel(const float* __restrict__ gate, u16* __restrict__ upact) {
  __shared__ u32 sabs[DFFN];       // silu(gate) f32 bits
  __shared__ u32 hist[4][256];
  __shared__ u32 ss[257];
  __shared__ u32 sh_prefix, sh_rem;
  const int tid = threadIdx.x, wave = tid >> 6;
  const size_t row = blockIdx.x;
  const float* g = gate + row * DFFN;
  for (int it = 0; it < 4; ++it) {
    int e = it * 2048 + tid * 8;
    float4 a = *(const float4*)(g + e);
    float4 b = *(const float4*)(g + e + 4);
    sabs[e + 0] = __builtin_bit_cast(u32, a.x);
    sabs[e + 1] = __builtin_bit_cast(u32, a.y);
    sabs[e + 2] = __builtin_bit_cast(u32, a.z);
    sabs[e + 3] = __builtin_bit_cast(u32, a.w);
    sabs[e + 4] = __builtin_bit_cast(u32, b.x);
    sabs[e + 5] = __builtin_bit_cast(u32, b.y);
    sabs[e + 6] = __builtin_bit_cast(u32, b.z);
    sabs[e + 7] = __builtin_bit_cast(u32, b.w);
  }
  if (tid == 0) { sh_prefix = 0; sh_rem = KKEEP; }
  __syncthreads();
  for (int pass = 0; pass < 4; ++pass) {
    const int p = 24 - pass * 8;
    const u32 mask_hi = (pass == 0) ? 0u : (0xFFFFFFFFu << (p + 8));
    for (int i = tid; i < 1024; i += 256) ((u32*)hist)[i] = 0;
    __syncthreads();
    const u32 prefix = sh_prefix, rem = sh_rem;
    for (int it = 0; it < 4; ++it) {
      int e = it * 2048 + tid * 8;
#pragma unroll
      for (int j = 0; j < 8; ++j) {
        u32 mg = sabs[e + j] & 0x7FFFFFFFu;
        if ((mg & mask_hi) == (prefix & mask_hi))
          atomicAdd(&hist[wave][(mg >> p) & 0xFF], 1u);
      }
    }
    __syncthreads();
    ss[tid] = hist[0][tid] + hist[1][tid] + hist[2][tid] + hist[3][tid];
    if (tid == 0) ss[256] = 0;
    __syncthreads();
    for (int off = 1; off < 256; off <<= 1) {
      u32 v = (tid + off < 256) ? ss[tid + off] : 0u;
      __syncthreads();
      ss[tid] += v;
      __syncthreads();
    }
    if (ss[tid] >= rem && ss[tid + 1] < rem) {
      sh_prefix = prefix | ((u32)tid << p);
      sh_rem = rem - ss[tid + 1];
    }
    __syncthreads();
  }
  const u32 thr = sh_prefix;
  u16* ua = upact + row * DFFN;
  for (int it = 0; it < 4; ++it) {
    int e = it * 2048 + tid * 8;
    uint4 uv = *(const uint4*)(ua + e);
    const u16* up16 = (const u16*)&uv;
    u16 outp[8];
#pragma unroll
    for (int j = 0; j < 8; ++j) {
      u32 bits = sabs[e + j];
      u32 mg = bits & 0x7FFFFFFFu;
      float gg = __builtin_bit_cast(float, bits);
      float prod = (mg >= thr) ? gg * b2f(up16[j]) : 0.0f;
      outp[j] = f2bu(prod);
    }
    uint4 ov;
    ov.x = (u32)outp[0] | ((u32)outp[1] << 16);
    ov.y = (u32)outp[2] | ((u32)outp[3] << 16);
    ov.z = (u32)outp[4] | ((u32)outp[5] << 16);
    ov.w = (u32)outp[6] | ((u32)outp[7] << 16);
    *(uint4*)(ua + e) = ov;
  }
}

// ---------------- launcher ----------------
extern "C" void kernel_launch(void* const* d_in, const int* in_sizes, int n_in,
                              void* d_out, int out_size, void* d_ws, size_t ws_size,
                              hipStream_t stream) {
  const float* hidden = (const float*)d_in[0];
  const float* wq = (const float*)d_in[1];
  const float* wk = (const float*)d_in[2];
  const float* wv = (const float*)d_in[3];
  const float* wo = (const float*)d_in[4];
  const float* ln1 = (const float*)d_in[5];
  const float* ln2 = (const float*)d_in[6];
  const float* wg = (const float*)d_in[7];
  const float* wu = (const float*)d_in[8];
  const float* wd = (const float*)d_in[9];
  float* out = (float*)d_out;
  (void)in_sizes; (void)n_in; (void)out_size;

  // ---- workspace layout (lifetime-aliased, ~196 MB total) ----
  size_t off = 0;
  auto alloc = [&](size_t n) { char* r = (char*)d_ws + off; off += (n + 255) & ~(size_t)255; return r; };
  u16* wq_b = (u16*)alloc((size_t)DMODEL * DMODEL * 2);      // 8 MB
  u16* wk_b = (u16*)alloc((size_t)NKVH * HDIM * DMODEL * 2); // 2 MB
  u16* wv_b = (u16*)alloc((size_t)NKVH * HDIM * DMODEL * 2); // 2 MB
  u16* wo_b = (u16*)alloc((size_t)DMODEL * DMODEL * 2);      // 8 MB
  u16* wg_b = (u16*)alloc((size_t)DFFN * DMODEL * 2);        // 32 MB
  u16* tok  = (u16*)alloc((size_t)MTOK * DMODEL * 2);        // 16 MB: x -> o -> y
  u16* upb  = (u16*)alloc((size_t)MTOK * DFFN * 2);          // 64 MB
  char* S   = alloc((size_t)(MTOK / 2) * DFFN * 4);          // 64 MB shared region
  // phase 1 of S: qb(16) kb(4) vtb(4) wu_b(32)
  u16* qb   = (u16*)S;
  u16* kb   = (u16*)(S + (size_t)MTOK * DMODEL * 2);
  u16* vtb  = (u16*)(S + (size_t)MTOK * DMODEL * 2 + (size_t)MTOK * NKVH * HDIM * 2);
  u16* wu_b = (u16*)(S + (size_t)MTOK * DMODEL * 2 + 2 * (size_t)MTOK * NKVH * HDIM * 2);
  // phase 2 of S: gate half (f32, 2048 x 8192)
  float* gateh = (float*)S;
  // phase 3 of S: wd_b (32 MB)
  u16* wd_b = (u16*)S;
  const size_t needed = off;
  if (ws_size < needed) return;  // clean fast-fail (diagnostic) instead of OOB hang

  auto cvt = [&](const float* src, u16* dst, size_t n) {
    cvt_kernel<<<dim3((unsigned)(n / 1024)), 256, 0, stream>>>(src, dst, (int)n);
  };
  cvt(wq, wq_b, (size_t)DMODEL * DMODEL);
  cvt(wk, wk_b, (size_t)NKVH * HDIM * DMODEL);
  cvt(wv, wv_b, (size_t)NKVH * HDIM * DMODEL);
  cvt(wo, wo_b, (size_t)DMODEL * DMODEL);
  cvt(wg, wg_b, (size_t)DFFN * DMODEL);
  cvt(wu, wu_b, (size_t)DFFN * DMODEL);

  // x = rmsnorm(hidden, ln1)
  rmsnorm_kernel<<<MTOK, 256, 0, stream>>>(hidden, ln1, tok);

  gemm_bt<0><<<dim3(DMODEL / 128, MTOK / 128), 256, 0, stream>>>(
      tok, wq_b, qb, nullptr, MTOK, DMODEL, DMODEL);
  gemm_bt<0><<<dim3(NKVH * HDIM / 128, MTOK / 128), 256, 0, stream>>>(
      tok, wk_b, kb, nullptr, MTOK, NKVH * HDIM, DMODEL);
  gemm_bt<1><<<dim3(NKVH * HDIM / 128, MTOK / 128), 256, 0, stream>>>(
      tok, wv_b, vtb, nullptr, MTOK, NKVH * HDIM, DMODEL);

  // o -> tok (x dead)
  attn_kernel<<<dim3(SEQ / 128, NHEADS, BATCH), 256, 0, stream>>>(qb, kb, vtb, tok);

  // h = hidden + o @ wo^T   -> stored in d_out
  gemm_bt<2><<<dim3(DMODEL / 128, MTOK / 128), 256, 0, stream>>>(
      tok, wo_b, out, hidden, MTOK, DMODEL, DMODEL);

  // y = rmsnorm(h, ln2) -> tok (o dead)
  rmsnorm_kernel<<<MTOK, 256, 0, stream>>>(out, ln2, tok);

  // up = y @ wu^T (bf16) — must complete before S is reused for gate halves
  gemm_bt<0><<<dim3(DFFN / 128, MTOK / 128), 256, 0, stream>>>(
      tok, wu_b, upb, nullptr, MTOK, DFFN, DMODEL);

  // gate halves: silu(y @ wg^T) f32 -> topk+multiply in-place into upb
  for (int half = 0; half < 2; ++half) {
    const u16* yh = tok + (size_t)half * (MTOK / 2) * DMODEL;
    u16* uph = upb + (size_t)half * (MTOK / 2) * DFFN;
    gemm_bt<3><<<dim3(DFFN / 128, (MTOK / 2) / 128), 256, 0, stream>>>(
        yh, wg_b, gateh, nullptr, MTOK / 2, DFFN, DMODEL);
    topk_kernel<<<MTOK / 2, 256, 0, stream>>>(gateh, uph);
  }

  // wd -> bf16 (into S, gate halves dead)
  cvt(wd, wd_b, (size_t)DMODEL * DFFN);

  // out = h + act @ wd^T  (in-place residual over d_out)
  gemm_bt<2><<<dim3(DMODEL / 128, MTOK / 128), 256, 0, stream>>>(
      upb, wd_b, out, out, MTOK, DMODEL, DFFN);
}

// Round 6
// 1036.912 us; speedup vs baseline: 1.1543x; 1.0147x over previous
//
#include <hip/hip_runtime.h>
#include <stdint.h>

constexpr int SEQ    = 2048;
constexpr int DMODEL = 2048;
constexpr int NHEADS = 16;
constexpr int NKVH   = 4;
constexpr int HDIM   = 128;
constexpr int DFFN   = 8192;
constexpr int BATCH  = 2;
constexpr int MTOK   = BATCH * SEQ;   // 4096 tokens
constexpr int KKEEP  = DFFN / 2;      // 4096

typedef __bf16 bf16x8 __attribute__((ext_vector_type(8)));
typedef float  f32x4  __attribute__((ext_vector_type(4)));
typedef float  f32x16 __attribute__((ext_vector_type(16)));
typedef unsigned short u16;
typedef unsigned int   u32;

__device__ __forceinline__ u16 f2bu(float f) {  // f32 -> bf16 bits, RNE
  u32 x = __builtin_bit_cast(u32, f);
  return (u16)((x + 0x7FFFu + ((x >> 16) & 1u)) >> 16);
}
__device__ __forceinline__ float b2f(u16 u) {
  u32 v = ((u32)u) << 16;
  return __builtin_bit_cast(float, v);
}
__device__ __forceinline__ void gl_lds16(const void* g, void* l) {
  // 16B per lane; LDS dest = wave-uniform base + lane*16
  __builtin_amdgcn_global_load_lds((const __attribute__((address_space(1))) u32*)g,
                                   (__attribute__((address_space(3))) u32*)l, 16, 0, 0);
}

// ---------------- weight convert f32 -> bf16 ----------------
__global__ __launch_bounds__(256) void cvt_kernel(const float* __restrict__ in,
                                                  u16* __restrict__ out, int n) {
  int i = (blockIdx.x * 256 + threadIdx.x) * 4;
  if (i >= n) return;
  float4 v = *(const float4*)(in + i);
  uint2 pk;
  pk.x = (u32)f2bu(v.x) | ((u32)f2bu(v.y) << 16);
  pk.y = (u32)f2bu(v.z) | ((u32)f2bu(v.w) << 16);
  *(uint2*)(out + i) = pk;
}

// ---------------- RMSNorm: f32 row -> bf16 row ----------------
__global__ __launch_bounds__(256) void rmsnorm_kernel(const float* __restrict__ in,
                                                      const float* __restrict__ w,
                                                      u16* __restrict__ out) {
  const int tid = threadIdx.x;
  const size_t row = blockIdx.x;
  const float* x = in + row * DMODEL;
  float4 v0 = *(const float4*)(x + tid * 4);
  float4 v1 = *(const float4*)(x + 1024 + tid * 4);
  float s = v0.x*v0.x + v0.y*v0.y + v0.z*v0.z + v0.w*v0.w
          + v1.x*v1.x + v1.y*v1.y + v1.z*v1.z + v1.w*v1.w;
#pragma unroll
  for (int off = 1; off < 64; off <<= 1) s += __shfl_xor(s, off, 64);
  __shared__ float wsum[4];
  if ((tid & 63) == 0) wsum[tid >> 6] = s;
  __syncthreads();
  s = wsum[0] + wsum[1] + wsum[2] + wsum[3];
  const float rinv = rsqrtf(s * (1.0f / DMODEL) + 1e-6f);
  u16* o = out + row * DMODEL;
#pragma unroll
  for (int part = 0; part < 2; ++part) {
    int c = part * 1024 + tid * 4;
    float4 vv = (part == 0) ? v0 : v1;
    float4 wv = *(const float4*)(w + c);
    uint2 pk;
    pk.x = (u32)f2bu(vv.x * rinv * wv.x) | ((u32)f2bu(vv.y * rinv * wv.y) << 16);
    pk.y = (u32)f2bu(vv.z * rinv * wv.z) | ((u32)f2bu(vv.w * rinv * wv.w) << 16);
    *(uint2*)(o + c) = pk;
  }
}

// ---------------- GEMM C[M,N] = A[M,K] @ B[N,K]^T (bf16 row-major) --------
// Min-2-phase pipeline (T3 minimum recipe): BK=64, double-buffered LDS,
// ONE raw barrier per K-step. Iter t: issue STAGE(t+1) into buf[(t+1)&1],
// then ds_read+32xMFMA from buf[t&1] (covers ~300cy of load flight), then
// vmcnt(0) (staged tile landed) + s_barrier (all waves done reading buf[t&1]
// -> next iter may overwrite it). Cross-wave visibility: each wave drains its
// own loads pre-barrier; barrier publishes.
// LDS chunk-XOR layout: row-major [row][8 chunks of 16B], slot c holds global
// chunk c^(row&7)  (measured 0 bank conflicts).
// EPI: 0 = bf16 store, 1 = transposed V store, 2 = f32 + residual (res may
//      alias C), 3 = f32 silu
template <int EPI>
__global__ __launch_bounds__(256, 2)
void gemm_bt(const u16* __restrict__ A, const u16* __restrict__ B,
             void* __restrict__ C, const float* res,
             int M, int N, int K) {
  __shared__ u16 As[2][128 * 64];
  __shared__ u16 Bs[2][128 * 64];
  const int tid = threadIdx.x;
  const int wave = tid >> 6, lane = tid & 63;
  // XCD-aware block swizzle (T1); all grids have nwg % 8 == 0
  const int nwg = gridDim.x * gridDim.y;
  const int lin = blockIdx.y * gridDim.x + blockIdx.x;
  const int swz = (lin & 7) * (nwg >> 3) + (lin >> 3);
  const int m0 = (swz / gridDim.x) * 128, n0 = (swz % gridDim.x) * 128;
  const int r_in = lane >> 3, chk = lane & 7;   // staging: 8 rows x 8 chunks / KB
  const int fk = lane >> 4, fc = lane & 15;     // MFMA fragment indices
  const int wm = (wave >> 1) * 64, wn = (wave & 1) * 64;
  const int nt = K >> 6;
  f32x4 acc[4][4] = {};

  auto stage = [&](int buf, int t) {
    const int kt = t * 64;
#pragma unroll
    for (int i = 0; i < 4; ++i) {
      int row = wave * 32 + i * 8 + r_in;
      int gc = chk ^ (row & 7);   // pre-swizzled source, linear LDS dest
      gl_lds16(A + (size_t)(m0 + row) * K + kt + gc * 8, &As[buf][(wave * 32 + i * 8) * 64]);
    }
#pragma unroll
    for (int i = 0; i < 4; ++i) {
      int row = wave * 32 + i * 8 + r_in;
      int gc = chk ^ (row & 7);
      gl_lds16(B + (size_t)(n0 + row) * K + kt + gc * 8, &Bs[buf][(wave * 32 + i * 8) * 64]);
    }
  };

  stage(0, 0);
  asm volatile("s_waitcnt vmcnt(0)" ::: "memory");
  __builtin_amdgcn_s_barrier();

  for (int t = 0; t < nt; ++t) {
    if (t + 1 < nt) stage((t + 1) & 1, t + 1);   // issue-early: overlaps MFMA below
    const u16* Ab = As[t & 1];
    const u16* Bb = Bs[t & 1];
#pragma unroll
    for (int kk = 0; kk < 2; ++kk) {
      bf16x8 a[4], b[4];
#pragma unroll
      for (int i = 0; i < 4; ++i) {
        int row = wm + i * 16 + fc;
        int c = (kk * 4 + fk) ^ (row & 7);
        a[i] = *(const bf16x8*)(Ab + row * 64 + c * 8);
      }
#pragma unroll
      for (int j = 0; j < 4; ++j) {
        int row = wn + j * 16 + fc;
        int c = (kk * 4 + fk) ^ (row & 7);
        b[j] = *(const bf16x8*)(Bb + row * 64 + c * 8);
      }
#pragma unroll
      for (int i = 0; i < 4; ++i)
#pragma unroll
        for (int j = 0; j < 4; ++j)
          acc[i][j] = __builtin_amdgcn_mfma_f32_16x16x32_bf16(a[i], b[j], acc[i][j], 0, 0, 0);
    }
    asm volatile("s_waitcnt vmcnt(0)" ::: "memory");  // staged loads landed (late drain)
    __builtin_amdgcn_s_barrier();
  }

  const int rb = fk * 4;  // C/D: col = lane&15, row = (lane>>4)*4 + reg
#pragma unroll
  for (int i = 0; i < 4; ++i) {
#pragma unroll
    for (int j = 0; j < 4; ++j) {
      int row = m0 + wm + i * 16 + rb;
      int col = n0 + wn + j * 16 + fc;
      f32x4 v = acc[i][j];
      if constexpr (EPI == 0) {
        u16* o = (u16*)C;
#pragma unroll
        for (int r = 0; r < 4; ++r) o[(size_t)(row + r) * N + col] = f2bu(v[r]);
      } else if constexpr (EPI == 1) {
        // vt[b][kvh][d][s] ; row = token (4 consecutive s), col = kvh*128+d
        u16* o = (u16*)C;
        int bb = row >> 11, s = row & (SEQ - 1);
        int kvh = col >> 7, d = col & (HDIM - 1);
        size_t base = (((size_t)bb * NKVH + kvh) * HDIM + d) * SEQ + s;
        uint2 pk;
        pk.x = (u32)f2bu(v[0]) | ((u32)f2bu(v[1]) << 16);
        pk.y = (u32)f2bu(v[2]) | ((u32)f2bu(v[3]) << 16);
        *(uint2*)(o + base) = pk;
      } else if constexpr (EPI == 2) {
        float* o = (float*)C;
#pragma unroll
        for (int r = 0; r < 4; ++r) {
          size_t idx = (size_t)(row + r) * N + col;
          float rv = res[idx];
          o[idx] = v[r] + rv;
        }
      } else {  // EPI == 3 : silu
        float* o = (float*)C;
#pragma unroll
        for (int r = 0; r < 4; ++r) {
          float g = v[r];
          o[(size_t)(row + r) * N + col] = g / (1.0f + __expf(-g));
        }
      }
    }
  }
}

// ---------------- flash attention (causal GQA, swapped-QK, 32x32 MFMA) -----
// block = 4 waves; wave w owns q-strip [bx*128 + 32w, +32). KVBLK=32.
// S^T = mfma(K, Q): lane owns q-col (lane&31); 16 kv-scores per lane.
__global__ __launch_bounds__(256, 2)
void attn_kernel(const u16* __restrict__ Q, const u16* __restrict__ Kb,
                 const u16* __restrict__ Vt, u16* __restrict__ O) {
  __shared__ u16 Ksh[2 * 32 * 128];   // [buf][kv][d], chunk^(kv&15) swizzle
  __shared__ u16 Vsh[2 * 128 * 32];   // [buf][d][kv], chunk^((d>>1)&3) swizzle
  const int tid = threadIdx.x, wave = tid >> 6, lane = tid & 63;
  const int half = lane >> 5, l31 = lane & 31;
  // XCD swizzle: dispatch d -> logical block (d%8)*64 + d/8 so each XCD
  // owns exactly one (b,kvh) -> its 1MB K+V stays in that XCD's L2.
  const int d_lin = blockIdx.x + gridDim.x * (blockIdx.y + gridDim.y * blockIdx.z);
  const int lin = (d_lin & 7) * 64 + (d_lin >> 3);
  const int bx = lin & 15, h = (lin >> 4) & 15, b = lin >> 8;
  const int kvh = h >> 2;
  const int qw = bx * 128 + wave * 32;
  const float SC = 0.08838834764831845f;  // 1/sqrt(128)
  const int ntb = bx * 4 + 4;             // staged tiles per block
  const int nmy = bx * 4 + wave;          // last tile index this wave computes

  // persistent Q fragments: qf[s] lane: Q[qw + l31][s*16 + half*8 + j]
  bf16x8 qf[8];
  {
    const u16* qp = Q + ((size_t)(b * SEQ + qw + l31)) * DMODEL + h * HDIM + half * 8;
#pragma unroll
    for (int s = 0; s < 8; ++s) qf[s] = *(const bf16x8*)(qp + s * 16);
  }
  f32x16 oacc[4] = {};
  float m_run = -1e30f, l_run = 0.0f;
  const size_t vbase = ((size_t)(b * NKVH + kvh)) * HDIM * SEQ;
  const u16* kbase = Kb + (size_t)b * SEQ * (NKVH * HDIM) + kvh * HDIM;

  auto stage = [&](int bi, int k0) {
    u16* Kd = Ksh + bi * 4096;
    u16* Vd = Vsh + bi * 4096;
#pragma unroll
    for (int ii = 0; ii < 2; ++ii) {
      int inst = wave * 2 + ii;
      {  // K: instr covers kv rows 4*inst..+3, 256B each
        int row = inst * 4 + (lane >> 4);
        int c = (lane & 15) ^ (row & 15);
        gl_lds16(kbase + (size_t)(k0 + row) * (NKVH * HDIM) + c * 8, Kd + inst * 512);
      }
      {  // V^T: instr covers d rows 16*inst..+15, 64B each
        int row = inst * 16 + (lane >> 2);
        int c = (lane & 3) ^ ((row >> 1) & 3);
        gl_lds16(Vt + vbase + (size_t)row * SEQ + k0 + c * 8, Vd + inst * 512);
      }
    }
  };

  stage(0, 0);
  __syncthreads();

  for (int t = 0; t < ntb; ++t) {
    if (t + 1 < ntb) stage((t + 1) & 1, (t + 1) * 32);
    if (t <= nmy) {
      const u16* Kd = Ksh + (t & 1) * 4096;
      const u16* Vd = Vsh + (t & 1) * 4096;
      // ---- S^T[kv][q] over d=128 ----
      f32x16 st = {};
#pragma unroll
      for (int s = 0; s < 8; ++s) {
        int c = (half + 2 * s) ^ (l31 & 15);
        bf16x8 kf = *(const bf16x8*)(Kd + l31 * 128 + c * 8);
        st = __builtin_amdgcn_mfma_f32_32x32x16_bf16(kf, qf[s], st, 0, 0, 0);
      }
      // ---- softmax (lane owns q = qw + l31; kv(r) = (r&3)+8*(r>>2)+4*half)
      const bool diag = (t * 32 == qw);
      float sv[16];
#pragma unroll
      for (int r = 0; r < 16; ++r) {
        float x = st[r] * SC;
        if (diag) {
          int kvl = (r & 3) + 8 * (r >> 2) + 4 * half;
          if (kvl > l31) x = -1e30f;
        }
        sv[r] = x;
      }
      float mx = sv[0];
#pragma unroll
      for (int r = 1; r < 16; ++r) mx = fmaxf(mx, sv[r]);
      mx = fmaxf(mx, __shfl_xor(mx, 32, 64));
      if (__any(mx > m_run + 4.0f)) {   // defer-max (exact): rescale rarely
        float mnew = fmaxf(m_run, mx);
        float alpha = __expf(m_run - mnew);
        m_run = mnew;
        l_run *= alpha;
#pragma unroll
        for (int r = 0; r < 16; ++r) {
          float ar = __shfl(alpha, (r & 3) + 8 * (r >> 2) + 4 * half, 64);
#pragma unroll
          for (int dt = 0; dt < 4; ++dt) oacc[dt][r] *= ar;
        }
      }
      float p[16];
      float rs = 0.0f;
#pragma unroll
      for (int r = 0; r < 16; ++r) { p[r] = __expf(sv[r] - m_run); rs += p[r]; }
      rs += __shfl_xor(rs, 32, 64);
      l_run += rs;
      // ---- P -> bf16 A-fragments via half-swap ----
      u32 c01 = (u32)f2bu(p[0])  | ((u32)f2bu(p[1])  << 16);
      u32 c23 = (u32)f2bu(p[2])  | ((u32)f2bu(p[3])  << 16);
      u32 c45 = (u32)f2bu(p[4])  | ((u32)f2bu(p[5])  << 16);
      u32 c67 = (u32)f2bu(p[6])  | ((u32)f2bu(p[7])  << 16);
      u32 c89 = (u32)f2bu(p[8])  | ((u32)f2bu(p[9])  << 16);
      u32 cAB = (u32)f2bu(p[10]) | ((u32)f2bu(p[11]) << 16);
      u32 cCD = (u32)f2bu(p[12]) | ((u32)f2bu(p[13]) << 16);
      u32 cEF = (u32)f2bu(p[14]) | ((u32)f2bu(p[15]) << 16);
      u32 paw[2][4];
      {
        u32 sA = __shfl_xor(c01, 32, 64), sB = __shfl_xor(c23, 32, 64);
        u32 sC = __shfl_xor(c45, 32, 64), sD = __shfl_xor(c67, 32, 64);
        paw[0][0] = half ? sC : c01;  paw[0][1] = half ? sD : c23;
        paw[0][2] = half ? c45 : sA;  paw[0][3] = half ? c67 : sB;
      }
      {
        u32 sA = __shfl_xor(c89, 32, 64), sB = __shfl_xor(cAB, 32, 64);
        u32 sC = __shfl_xor(cCD, 32, 64), sD = __shfl_xor(cEF, 32, 64);
        paw[1][0] = half ? sC : c89;  paw[1][1] = half ? sD : cAB;
        paw[1][2] = half ? cCD : sA;  paw[1][3] = half ? cEF : sB;
      }
      // ---- PV: oacc[dt][q-rows] += P[q][kv] * V[kv][d] ----
#pragma unroll
      for (int ks = 0; ks < 2; ++ks) {
        bf16x8 paf = __builtin_bit_cast(bf16x8, *(uint4*)&paw[ks][0]);
#pragma unroll
        for (int dt = 0; dt < 4; ++dt) {
          int row = dt * 32 + l31;
          int c = (half + 2 * ks) ^ ((row >> 1) & 3);
          bf16x8 vf = *(const bf16x8*)(Vd + row * 32 + c * 8);
          oacc[dt] = __builtin_amdgcn_mfma_f32_32x32x16_bf16(paf, vf, oacc[dt], 0, 0, 0);
        }
      }
    }
    __syncthreads();
  }

  // ---- epilogue: O[q][d] / l[q] ----
  float rinv = 1.0f / l_run;
  u16* ob = O + ((size_t)(b * SEQ + qw)) * DMODEL + h * HDIM + l31;
#pragma unroll
  for (int r = 0; r < 16; ++r) {
    int qr = (r & 3) + 8 * (r >> 2) + 4 * half;
    float ir = __shfl(rinv, qr, 64);
#pragma unroll
    for (int dt = 0; dt < 4; ++dt)
      ob[(size_t)qr * DMODEL + dt * 32] = f2bu(oacc[dt][r] * ir);
  }
}

// ---------------- top-k (exact radix select) + gate*up, in-place over up ---
__global__ __launch_bounds__(256)
void topk_kernel(const float* __restrict__ gate, u16* __restrict__ upact) {
  __shared__ u32 sabs[DFFN];       // silu(gate) f32 bits
  __shared__ u32 hist[4][256];
  __shared__ u32 ss[257];
  __shared__ u32 sh_prefix, sh_rem;
  const int tid = threadIdx.x, wave = tid >> 6;
  const size_t row = blockIdx.x;
  const float* g = gate + row * DFFN;
  for (int it = 0; it < 4; ++it) {
    int e = it * 2048 + tid * 8;
    float4 a = *(const float4*)(g + e);
    float4 b = *(const float4*)(g + e + 4);
    sabs[e + 0] = __builtin_bit_cast(u32, a.x);
    sabs[e + 1] = __builtin_bit_cast(u32, a.y);
    sabs[e + 2] = __builtin_bit_cast(u32, a.z);
    sabs[e + 3] = __builtin_bit_cast(u32, a.w);
    sabs[e + 4] = __builtin_bit_cast(u32, b.x);
    sabs[e + 5] = __builtin_bit_cast(u32, b.y);
    sabs[e + 6] = __builtin_bit_cast(u32, b.z);
    sabs[e + 7] = __builtin_bit_cast(u32, b.w);
  }
  if (tid == 0) { sh_prefix = 0; sh_rem = KKEEP; }
  __syncthreads();
  for (int pass = 0; pass < 4; ++pass) {
    const int p = 24 - pass * 8;
    const u32 mask_hi = (pass == 0) ? 0u : (0xFFFFFFFFu << (p + 8));
    for (int i = tid; i < 1024; i += 256) ((u32*)hist)[i] = 0;
    __syncthreads();
    const u32 prefix = sh_prefix, rem = sh_rem;
    for (int it = 0; it < 4; ++it) {
      int e = it * 2048 + tid * 8;
#pragma unroll
      for (int j = 0; j < 8; ++j) {
        u32 mg = sabs[e + j] & 0x7FFFFFFFu;
        if ((mg & mask_hi) == (prefix & mask_hi))
          atomicAdd(&hist[wave][(mg >> p) & 0xFF], 1u);
      }
    }
    __syncthreads();
    ss[tid] = hist[0][tid] + hist[1][tid] + hist[2][tid] + hist[3][tid];
    if (tid == 0) ss[256] = 0;
    __syncthreads();
    for (int off = 1; off < 256; off <<= 1) {
      u32 v = (tid + off < 256) ? ss[tid + off] : 0u;
      __syncthreads();
      ss[tid] += v;
      __syncthreads();
    }
    if (ss[tid] >= rem && ss[tid + 1] < rem) {
      sh_prefix = prefix | ((u32)tid << p);
      sh_rem = rem - ss[tid + 1];
    }
    __syncthreads();
  }
  const u32 thr = sh_prefix;
  u16* ua = upact + row * DFFN;
  for (int it = 0; it < 4; ++it) {
    int e = it * 2048 + tid * 8;
    uint4 uv = *(const uint4*)(ua + e);
    const u16* up16 = (const u16*)&uv;
    u16 outp[8];
#pragma unroll
    for (int j = 0; j < 8; ++j) {
      u32 bits = sabs[e + j];
      u32 mg = bits & 0x7FFFFFFFu;
      float gg = __builtin_bit_cast(float, bits);
      float prod = (mg >= thr) ? gg * b2f(up16[j]) : 0.0f;
      outp[j] = f2bu(prod);
    }
    uint4 ov;
    ov.x = (u32)outp[0] | ((u32)outp[1] << 16);
    ov.y = (u32)outp[2] | ((u32)outp[3] << 16);
    ov.z = (u32)outp[4] | ((u32)outp[5] << 16);
    ov.w = (u32)outp[6] | ((u32)outp[7] << 16);
    *(uint4*)(ua + e) = ov;
  }
}

// ---------------- launcher ----------------
extern "C" void kernel_launch(void* const* d_in, const int* in_sizes, int n_in,
                              void* d_out, int out_size, void* d_ws, size_t ws_size,
                              hipStream_t stream) {
  const float* hidden = (const float*)d_in[0];
  const float* wq = (const float*)d_in[1];
  const float* wk = (const float*)d_in[2];
  const float* wv = (const float*)d_in[3];
  const float* wo = (const float*)d_in[4];
  const float* ln1 = (const float*)d_in[5];
  const float* ln2 = (const float*)d_in[6];
  const float* wg = (const float*)d_in[7];
  const float* wu = (const float*)d_in[8];
  const float* wd = (const float*)d_in[9];
  float* out = (float*)d_out;
  (void)in_sizes; (void)n_in; (void)out_size;

  // ---- workspace layout (lifetime-aliased, ~196 MB total) ----
  size_t off = 0;
  auto alloc = [&](size_t n) { char* r = (char*)d_ws + off; off += (n + 255) & ~(size_t)255; return r; };
  u16* wq_b = (u16*)alloc((size_t)DMODEL * DMODEL * 2);      // 8 MB
  u16* wk_b = (u16*)alloc((size_t)NKVH * HDIM * DMODEL * 2); // 2 MB
  u16* wv_b = (u16*)alloc((size_t)NKVH * HDIM * DMODEL * 2); // 2 MB
  u16* wo_b = (u16*)alloc((size_t)DMODEL * DMODEL * 2);      // 8 MB
  u16* wg_b = (u16*)alloc((size_t)DFFN * DMODEL * 2);        // 32 MB
  u16* tok  = (u16*)alloc((size_t)MTOK * DMODEL * 2);        // 16 MB: x -> o -> y
  u16* upb  = (u16*)alloc((size_t)MTOK * DFFN * 2);          // 64 MB
  char* S   = alloc((size_t)(MTOK / 2) * DFFN * 4);          // 64 MB shared region
  // phase 1 of S: qb(16) kb(4) vtb(4) wu_b(32)
  u16* qb   = (u16*)S;
  u16* kb   = (u16*)(S + (size_t)MTOK * DMODEL * 2);
  u16* vtb  = (u16*)(S + (size_t)MTOK * DMODEL * 2 + (size_t)MTOK * NKVH * HDIM * 2);
  u16* wu_b = (u16*)(S + (size_t)MTOK * DMODEL * 2 + 2 * (size_t)MTOK * NKVH * HDIM * 2);
  // phase 2 of S: gate half (f32, 2048 x 8192)
  float* gateh = (float*)S;
  // phase 3 of S: wd_b (32 MB)
  u16* wd_b = (u16*)S;
  const size_t needed = off;
  if (ws_size < needed) return;  // clean fast-fail (diagnostic) instead of OOB hang

  auto cvt = [&](const float* src, u16* dst, size_t n) {
    cvt_kernel<<<dim3((unsigned)(n / 1024)), 256, 0, stream>>>(src, dst, (int)n);
  };
  cvt(wq, wq_b, (size_t)DMODEL * DMODEL);
  cvt(wk, wk_b, (size_t)NKVH * HDIM * DMODEL);
  cvt(wv, wv_b, (size_t)NKVH * HDIM * DMODEL);
  cvt(wo, wo_b, (size_t)DMODEL * DMODEL);
  cvt(wg, wg_b, (size_t)DFFN * DMODEL);
  cvt(wu, wu_b, (size_t)DFFN * DMODEL);

  // x = rmsnorm(hidden, ln1)
  rmsnorm_kernel<<<MTOK, 256, 0, stream>>>(hidden, ln1, tok);

  gemm_bt<0><<<dim3(DMODEL / 128, MTOK / 128), 256, 0, stream>>>(
      tok, wq_b, qb, nullptr, MTOK, DMODEL, DMODEL);
  gemm_bt<0><<<dim3(NKVH * HDIM / 128, MTOK / 128), 256, 0, stream>>>(
      tok, wk_b, kb, nullptr, MTOK, NKVH * HDIM, DMODEL);
  gemm_bt<1><<<dim3(NKVH * HDIM / 128, MTOK / 128), 256, 0, stream>>>(
      tok, wv_b, vtb, nullptr, MTOK, NKVH * HDIM, DMODEL);

  // o -> tok (x dead)
  attn_kernel<<<dim3(SEQ / 128, NHEADS, BATCH), 256, 0, stream>>>(qb, kb, vtb, tok);

  // h = hidden + o @ wo^T   -> stored in d_out
  gemm_bt<2><<<dim3(DMODEL / 128, MTOK / 128), 256, 0, stream>>>(
      tok, wo_b, out, hidden, MTOK, DMODEL, DMODEL);

  // y = rmsnorm(h, ln2) -> tok (o dead)
  rmsnorm_kernel<<<MTOK, 256, 0, stream>>>(out, ln2, tok);

  // up = y @ wu^T (bf16) — must complete before S is reused for gate halves
  gemm_bt<0><<<dim3(DFFN / 128, MTOK / 128), 256, 0, stream>>>(
      tok, wu_b, upb, nullptr, MTOK, DFFN, DMODEL);

  // gate halves: silu(y @ wg^T) f32 -> topk+multiply in-place into upb
  for (int half = 0; half < 2; ++half) {
    const u16* yh = tok + (size_t)half * (MTOK / 2) * DMODEL;
    u16* uph = upb + (size_t)half * (MTOK / 2) * DFFN;
    gemm_bt<3><<<dim3(DFFN / 128, (MTOK / 2) / 128), 256, 0, stream>>>(
        yh, wg_b, gateh, nullptr, MTOK / 2, DFFN, DMODEL);
    topk_kernel<<<MTOK / 2, 256, 0, stream>>>(gateh, uph);
  }

  // wd -> bf16 (into S, gate halves dead)
  cvt(wd, wd_b, (size_t)DMODEL * DFFN);

  // out = h + act @ wd^T  (in-place residual over d_out)
  gemm_bt<2><<<dim3(DMODEL / 128, MTOK / 128), 256, 0, stream>>>(
      upb, wd_b, out, out, MTOK, DMODEL, DFFN);
}